// Round 6
// baseline (206.397 us; speedup 1.0000x reference)
//
#include <hip/hip_runtime.h>
#include <hip/hip_bf16.h>

// Problem constants (match setup_inputs): B=2, N=512, D=128, H=256.
#define BB 2
#define NN 512
#define DD 128
#define HH 256

typedef __attribute__((ext_vector_type(4))) float    f32x4;
typedef __attribute__((ext_vector_type(8))) _Float16 f16x8;  // 4 VGPRs
typedef __attribute__((ext_vector_type(4))) int      i32x4;

// VALU-pipe 16-lane reduce step (DPP).
template <int CTRL>
__device__ __forceinline__ float dpp_add(float x) {
  int s = __builtin_amdgcn_update_dpp(0, __float_as_int(x), CTRL, 0xF, 0xF, true);
  return x + __int_as_float(s);
}

// ---------------------------------------------------------------------------
// Stage 1 (+W2 prep in extra blocks):
//   hA[b,n,h] = f16(b1[h] + sum_d PhiA*W1[:D]);  hB = f16(PhiB*W1[D:])
//   W2t[col][k] = f16(W2[k][col])
// ---------------------------------------------------------------------------
#define S1_ROWS 8
#define S1_BLOCKS (2 * (BB * NN) / S1_ROWS)  // 512
__global__ __launch_bounds__(256) void stage1(
    const float* __restrict__ PhiA, const float* __restrict__ PhiB,
    const float* __restrict__ W1,  const float* __restrict__ b1,
    const float* __restrict__ W2,
    _Float16* __restrict__ hA, _Float16* __restrict__ hB,
    _Float16* __restrict__ W2t) {
  if (blockIdx.x >= S1_BLOCKS) {  // W2 transpose+cast: 8 blocks
    const int bid2 = blockIdx.x - S1_BLOCKS;       // 0..7
    const int col  = bid2 * 32 + (threadIdx.x >> 3);
    const int k0   = (threadIdx.x & 7) * 32;
#pragma unroll
    for (int j = 0; j < 32; j++)
      W2t[col * HH + k0 + j] = (_Float16)W2[(k0 + j) * HH + col];
    return;
  }
  __shared__ float phis[S1_ROWS * DD];  // 4 KB
  const int side = blockIdx.x & 1;
  const int row0 = (blockIdx.x >> 1) * S1_ROWS;
  const float* Phi = side ? PhiB : PhiA;
  const float* W   = W1 + side * DD * HH;
  ((f32x4*)phis)[threadIdx.x] =
      ((const f32x4*)(Phi + (size_t)row0 * DD))[threadIdx.x];
  __syncthreads();
  const int h = threadIdx.x;
  float acc[S1_ROWS];
#pragma unroll
  for (int i = 0; i < S1_ROWS; i++) acc[i] = 0.f;
  for (int d0 = 0; d0 < DD; d0 += 4) {
    const float w0 = W[(d0 + 0) * HH + h];
    const float w1 = W[(d0 + 1) * HH + h];
    const float w2 = W[(d0 + 2) * HH + h];
    const float w3 = W[(d0 + 3) * HH + h];
#pragma unroll
    for (int i = 0; i < S1_ROWS; i++) {
      f32x4 ph = *(const f32x4*)&phis[i * DD + d0];
      acc[i] = fmaf(ph.x, w0, acc[i]);
      acc[i] = fmaf(ph.y, w1, acc[i]);
      acc[i] = fmaf(ph.z, w2, acc[i]);
      acc[i] = fmaf(ph.w, w3, acc[i]);
    }
  }
  const float bias = side ? 0.f : b1[h];
  _Float16* o = (side ? hB : hA) + (size_t)row0 * HH + h;
#pragma unroll
  for (int i = 0; i < S1_ROWS; i++) o[i * HH] = (_Float16)(acc[i] + bias);
}

// ---------------------------------------------------------------------------
// Main fused kernel, LDS-free A-path.
// 512 threads = 8 waves; wave w owns cols [w*32, w*32+32).
// Tile per iter: 16 pairs = (1 n-row) x (16 m-rows), m0 fixed per block.
// Lane (g,lr) builds A-fragment relu(hA[n][k]+hB[m0+lr][k]) in-register:
//   hbr[ks] loop-invariant (32 VGPRs), hA frag lr-independent (L1 broadcast).
// No h1 LDS, no ds_read/ds_write, no build barrier. Per iter: 16 MFMAs/wave,
// DPP col-reduce, red[] LDS (tiny) + 1 barrier, store deferred 1 iter.
// ---------------------------------------------------------------------------
#define GRID_MAIN 512
#define KITERS 64

__global__ __launch_bounds__(512, 4) void pairmlp(
    const _Float16* __restrict__ hA, const _Float16* __restrict__ hB,
    const _Float16* __restrict__ W2t, const float* __restrict__ b2,
    const float* __restrict__ W3, const float* __restrict__ b3,
    float* __restrict__ out) {
  __shared__ float red[2][8][16];  // per-wave col-partials, dbuf by parity

  const int tid  = threadIdx.x;
  const int lane = tid & 63;
  const int w    = tid >> 6;   // wave 0..7
  const int g    = lane >> 4;  // 0..3 (k-subgroup)
  const int lr   = lane & 15;  // A-row (= m) and B/D col within 16-tile
  const int bid  = blockIdx.x;
  const int bb    = bid >> 8;               // batch
  const int m0    = ((bid >> 3) & 31) * 16; // fixed per block
  const int nbase = bid & 7;                // 0..7; n = nbase + 8*k

  // ---- persistent W2 fragments: 8 ks x 2 ct = 64 VGPRs ----
  f16x8 breg[8][2];
#pragma unroll
  for (int ks = 0; ks < 8; ks++)
#pragma unroll
    for (int ct = 0; ct < 2; ct++) {
      const int col = w * 32 + ct * 16 + lr;
      breg[ks][ct] =
          *reinterpret_cast<const f16x8*>(&W2t[col * HH + ks * 32 + g * 8]);
    }
  // ---- loop-invariant hB fragments: 32 VGPRs ----
  f16x8 hbr[8];
  {
    const _Float16* hBp = hB + (size_t)(bb * NN + m0 + lr) * HH + g * 8;
#pragma unroll
    for (int ks = 0; ks < 8; ks++)
      hbr[ks] = *reinterpret_cast<const f16x8*>(hBp + ks * 32);
  }
  float b2v[2], w3v[2];
#pragma unroll
  for (int ct = 0; ct < 2; ct++) {
    const int col = w * 32 + ct * 16 + lr;
    b2v[ct] = b2[col];
    w3v[ct] = W3[col];
  }
  const float b3v = b3[0];

  // hA fragment base (lr-independent -> L1 broadcast within g-groups)
  const _Float16* hAp = hA + (size_t)(bb * NN + nbase) * HH + g * 8;
  const f16x8 zero8 = {};

  for (int k = 0; k < KITERS; k++) {
    const int cur = k & 1;

    // deferred store of previous iter's outputs (red[cur^1] sealed by the
    // barrier at the END of the previous iteration)
    if (k > 0 && tid < 16) {
      const int pb = cur ^ 1;
      float v = b3v;
#pragma unroll
      for (int ww = 0; ww < 8; ww++) v += red[pb][ww][tid];
      const int npr = nbase + 8 * (k - 1);
      out[(size_t)(bb * NN + npr) * NN + m0 + tid] = v;
    }

    // ---- build + MFMA, fully in-register ----
    const _Float16* hAk = hAp + (size_t)(8 * k) * HH;
    f32x4 acc[2];
    acc[0] = (f32x4){0.f, 0.f, 0.f, 0.f};
    acc[1] = (f32x4){0.f, 0.f, 0.f, 0.f};
#pragma unroll
    for (int ks = 0; ks < 8; ks++) {
      f16x8 ha = *reinterpret_cast<const f16x8*>(hAk + ks * 32);
      f16x8 af = __builtin_elementwise_max(ha + hbr[ks], zero8);
      acc[0] = __builtin_amdgcn_mfma_f32_16x16x32_f16(af, breg[ks][0], acc[0], 0, 0, 0);
      acc[1] = __builtin_amdgcn_mfma_f32_16x16x32_f16(af, breg[ks][1], acc[1], 0, 0, 0);
    }

    // ---- epilogue: relu(.+b2)*w3, DPP 16-lane col-reduce ----
#pragma unroll
    for (int r = 0; r < 4; r++) {
      float s = fmaxf(acc[0][r] + b2v[0], 0.f) * w3v[0];
      s = fmaf(fmaxf(acc[1][r] + b2v[1], 0.f), w3v[1], s);
      s = dpp_add<0xB1>(s);    // + lane^1
      s = dpp_add<0x4E>(s);    // + lane^2
      s = dpp_add<0x141>(s);   // + other quad (row_half_mirror)
      s = dpp_add<0x140>(s);   // + other 8-group (row_mirror)
      if (lr == 0) red[cur][w][g * 4 + r] = s;  // pair m = g*4+r
    }
    __syncthreads();  // seals red[cur] for next iter's store; also WAR on red[cur^1]
  }

  // tail: store the last iter's outputs
  if (tid < 16) {
    const int pb = (KITERS - 1) & 1;
    float v = b3v;
#pragma unroll
    for (int ww = 0; ww < 8; ww++) v += red[pb][ww][tid];
    const int nlast = nbase + 8 * (KITERS - 1);
    out[(size_t)(bb * NN + nlast) * NN + m0 + tid] = v;
  }
}

// ---------------------------------------------------------------------------
extern "C" void kernel_launch(void* const* d_in, const int* in_sizes, int n_in,
                              void* d_out, int out_size, void* d_ws, size_t ws_size,
                              hipStream_t stream) {
  const float* PhiA = (const float*)d_in[0];
  const float* PhiB = (const float*)d_in[1];
  const float* W1   = (const float*)d_in[2];
  const float* b1   = (const float*)d_in[3];
  const float* W2   = (const float*)d_in[4];
  const float* b2   = (const float*)d_in[5];
  const float* W3   = (const float*)d_in[6];
  const float* b3   = (const float*)d_in[7];
  float* out = (float*)d_out;

  char* ws = (char*)d_ws;
  _Float16* hA  = (_Float16*)ws;                    // 512 KB
  _Float16* hB  = (_Float16*)(ws + (512u << 10));   // 512 KB
  _Float16* W2t = (_Float16*)(ws + (1024u << 10));  // 128 KB

  hipLaunchKernelGGL(stage1, dim3(S1_BLOCKS + 8), dim3(256), 0, stream,
                     PhiA, PhiB, W1, b1, W2, hA, hB, W2t);
  hipLaunchKernelGGL(pairmlp, dim3(GRID_MAIN), dim3(512), 0, stream,
                     hA, hB, W2t, b2, W3, b3, out);
}